// Round 9
// baseline (250.815 us; speedup 1.0000x reference)
//
#include <hip/hip_runtime.h>
#include <hip/hip_bf16.h>

// CIA_56049323213169: channel attention
//   x (4,1024,64,64) f32.  X1 = flat viewed (1024,16384), X2 = flat viewed (16384,1024)
//   S = X1 @ X2 (1024x1024); attn = softmax_rows(S)
//   out = attn @ X1 (1024x16384); y = softmax_rows(out)
//   result = x + softmax_over_W64(y)
// Round 6 kernel, resubmitted (rounds 6-8 were infra failures, no data):
//   GEMM epilogue repacked through LDS (coalesced 16B C-stores, kills the
//   82MB-vs-32MB write amplification seen in round-5 counters); prep_t1/t2_bf16
//   vectorized (16B loads / 8B stores). GEMM main loop unchanged.

typedef __bf16 bf16x8 __attribute__((ext_vector_type(8)));
typedef float f32x4 __attribute__((ext_vector_type(4)));
typedef unsigned short u16;
typedef unsigned short u16x4 __attribute__((ext_vector_type(4)));
typedef unsigned short u16x8 __attribute__((ext_vector_type(8)));

#define DEV __device__ __forceinline__

DEV float bf2f(u16 u) { return __uint_as_float(((unsigned int)u) << 16); }
DEV u16 f2bf(float f) {  // RNE f32->bf16 (no NaN/Inf in this workload)
  unsigned int x = __float_as_uint(f);
  return (u16)((x + 0x7FFFu + ((x >> 16) & 1u)) >> 16);
}

DEV void gld16(const u16* g, u16* lds) {
  // async global->LDS, 16B per lane; LDS dest = wave-uniform base + lane*16
  __builtin_amdgcn_global_load_lds(
      (const __attribute__((address_space(1))) unsigned int*)g,
      (__attribute__((address_space(3))) unsigned int*)lds, 16, 0, 0);
}

// ---- prep: read x as (16384,1024) f32; emit A16 (cast) + Bt1 (transpose) ----
// block (16,32), tile 64x64: 16B loads, 8B stores both outputs.
__global__ __launch_bounds__(512) void prep_t1(const float* __restrict__ x,
                                               u16* __restrict__ A16,
                                               u16* __restrict__ Bt1) {
  __shared__ float tile[64][68];
  const int c0 = blockIdx.x * 64, r0 = blockIdx.y * 64;
  const int tx = threadIdx.x, ty = threadIdx.y;
#pragma unroll
  for (int h = 0; h < 2; ++h) {
    const int r = ty + h * 32;
    const size_t idx = (size_t)(r0 + r) * 1024 + c0 + tx * 4;
    float4 v = *reinterpret_cast<const float4*>(x + idx);
    tile[r][tx * 4 + 0] = v.x; tile[r][tx * 4 + 1] = v.y;
    tile[r][tx * 4 + 2] = v.z; tile[r][tx * 4 + 3] = v.w;
    u16x4 o;
    o[0] = f2bf(v.x); o[1] = f2bf(v.y); o[2] = f2bf(v.z); o[3] = f2bf(v.w);
    *reinterpret_cast<u16x4*>(A16 + idx) = o;
  }
  __syncthreads();
#pragma unroll
  for (int h = 0; h < 2; ++h) {
    const int c = ty + h * 32;
    u16x4 o;
    o[0] = f2bf(tile[tx * 4 + 0][c]); o[1] = f2bf(tile[tx * 4 + 1][c]);
    o[2] = f2bf(tile[tx * 4 + 2][c]); o[3] = f2bf(tile[tx * 4 + 3][c]);
    *reinterpret_cast<u16x4*>(Bt1 + (size_t)(c0 + c) * 16384 + r0 + tx * 4) = o;
  }
}

// ---- transpose2: A16 viewed (1024,16384) bf16 -> Bt2 (16384,1024) bf16 ----
__global__ __launch_bounds__(512) void t2_bf16(const u16* __restrict__ in,
                                               u16* __restrict__ out) {
  __shared__ u16 tile[64][72];
  const int c0 = blockIdx.x * 64, r0 = blockIdx.y * 64;
  const int tx = threadIdx.x, ty = threadIdx.y;
#pragma unroll
  for (int h = 0; h < 2; ++h) {
    const int r = ty + h * 32;
    *reinterpret_cast<u16x4*>(&tile[r][tx * 4]) =
        *reinterpret_cast<const u16x4*>(in + (size_t)(r0 + r) * 16384 + c0 + tx * 4);
  }
  __syncthreads();
#pragma unroll
  for (int h = 0; h < 2; ++h) {
    const int c = ty + h * 32;
    u16x4 o;
    o[0] = tile[tx * 4 + 0][c]; o[1] = tile[tx * 4 + 1][c];
    o[2] = tile[tx * 4 + 2][c]; o[3] = tile[tx * 4 + 3][c];
    *reinterpret_cast<u16x4*>(out + (size_t)(c0 + c) * 1024 + r0 + tx * 4) = o;
  }
}

// =====================================================================
// 256x256-tile 8-phase GEMM (main loop unchanged; LDS-repack epilogue new)
// =====================================================================

#define FENCE() asm volatile("" ::: "memory")
#define BAR()                           \
  {                                     \
    FENCE();                            \
    __builtin_amdgcn_s_barrier();       \
    __builtin_amdgcn_sched_barrier(0);  \
    FENCE();                            \
  }
#define LGKM0()                                          \
  {                                                      \
    asm volatile("s_waitcnt lgkmcnt(0)" ::: "memory");   \
    __builtin_amdgcn_sched_barrier(0);                   \
  }

#define DS_A(BUF, H, MG)                                        \
  {                                                             \
    const u16* Ab_ = &lds[(BUF)][0][(H)][0] + aoff + (MG)*2048; \
    a[0] = *(const bf16x8*)(Ab_);                               \
    a[1] = *(const bf16x8*)(Ab_ + 512);                         \
    a[2] = *(const bf16x8*)(Ab_ + 1024);                        \
    a[3] = *(const bf16x8*)(Ab_ + 1536);                        \
  }
#define DS_B(BUF, H)                                            \
  {                                                             \
    const u16* Bb_ = &lds[(BUF)][1][(H)][0] + boff;             \
    b[0] = *(const bf16x8*)(Bb_);                               \
    b[1] = *(const bf16x8*)(Bb_ + 512);                         \
    b[2] = *(const bf16x8*)(Bb_ + 1024);                        \
    b[3] = *(const bf16x8*)(Bb_ + 1536);                        \
  }
#define STAGE(BUF, MAT, H, KCOL, P, LD)        \
  {                                            \
    u16* d_ = &lds[(BUF)][(MAT)][(H)][0];      \
    gld16((P) + (KCOL), d_ + wb0);             \
    gld16((P) + (KCOL) + (LD), d_ + wb1);      \
  }
#define MMA(MG)                                                              \
  {                                                                          \
    __builtin_amdgcn_s_setprio(1);                                           \
    _Pragma("unroll") for (int i_ = 0; i_ < 4; ++i_) {                       \
      _Pragma("unroll") for (int n_ = 0; n_ < 4; ++n_)                       \
        acc[(MG)*4 + i_][n_] = __builtin_amdgcn_mfma_f32_16x16x32_bf16(      \
            a[i_], b[n_], acc[(MG)*4 + i_][n_], 0, 0, 0);                    \
    }                                                                        \
    __builtin_amdgcn_s_setprio(0);                                           \
  }

// One K-tile = 4 phases. W2/W4 are vmcnt immediates (token-pasted).
#define TILE(BC, BN, T, DO_S12, DO_S34, W2, W4)                      \
  {                                                                  \
    DS_A((BC), 0, 0); DS_B((BC), 0);                                 \
    if (DO_S12) STAGE((BN), 0, 1, ((T) + 1) * 64 + 32, pA, ldA128);  \
    BAR(); LGKM0(); MMA(0); BAR();                                   \
    DS_A((BC), 0, 1);                                                \
    if (DO_S12) STAGE((BN), 1, 1, ((T) + 1) * 64 + 32, pB, ldB128);  \
    asm volatile("s_waitcnt vmcnt(" #W2 ")" ::: "memory");           \
    BAR(); LGKM0(); MMA(1); BAR();                                   \
    DS_A((BC), 1, 0); DS_B((BC), 1);                                 \
    if (DO_S34) STAGE((BC), 0, 0, ((T) + 2) * 64, pA, ldA128);       \
    BAR(); LGKM0(); MMA(0); BAR();                                   \
    DS_A((BC), 1, 1);                                                \
    if (DO_S34) STAGE((BC), 1, 0, ((T) + 2) * 64, pB, ldB128);       \
    asm volatile("s_waitcnt vmcnt(" #W4 ")" ::: "memory");           \
    BAR(); LGKM0(); MMA(1); BAR();                                   \
  }

template <int MODE>
__global__ __launch_bounds__(512, 2) void gemm256(const u16* __restrict__ A,
                                                  const u16* __restrict__ Bt,
                                                  u16* __restrict__ C,
                                                  int lda, int ldbt, int ldc,
                                                  long zstride) {
  __shared__ __align__(16) u16 lds[2][2][2][8192];  // 128 KiB

  const int tid = threadIdx.x;
  const int w = tid >> 6, l = tid & 63;
  const int wr = w >> 2, wc = w & 3;

  // block decomposition with XCD-chunked swizzle (256 % 8 == 0 -> bijective)
  const int hw = blockIdx.x;
  const int logical = ((hw & 7) << 5) | (hw >> 3);
  int bx, by, z;
  if (MODE == 0) { bx = logical & 3; by = (logical >> 2) & 3; z = logical >> 4; }
  else           { by = logical & 3; bx = logical >> 2;       z = 0; }
  const int brow = by * 256, bcol = bx * 256;
  const int kbase = z << 10;

  const int srow = w * 16 + (l >> 2);
  const int swz = (((l & 3) ^ ((l >> 2) & 3) ^ ((l >> 4) & 1)) * 8);
  const u16* pA = A + (size_t)(brow + srow) * lda + kbase + swz;
  const u16* pB = Bt + (size_t)(bcol + srow) * ldbt + kbase + swz;
  const size_t ldA128 = (size_t)128 * lda, ldB128 = (size_t)128 * ldbt;
  const int wb0 = (w * 16) * 32, wb1 = (w * 16 + 128) * 32;

  const int slotp = (l >> 4) ^ (l & 3) ^ ((l >> 2) & 1);
  const int aoff = (wr * 128 + (l & 15)) * 32 + slotp * 8;
  const int boff = (wc * 64 + (l & 15)) * 32 + slotp * 8;

  STAGE(0, 0, 0, 0, pA, ldA128);
  STAGE(0, 1, 0, 0, pB, ldB128);
  STAGE(0, 0, 1, 32, pA, ldA128);
  STAGE(0, 1, 1, 32, pB, ldB128);
  STAGE(1, 0, 0, 64, pA, ldA128);
  STAGE(1, 1, 0, 64, pB, ldB128);

  f32x4 acc[8][4];
#pragma unroll
  for (int m = 0; m < 8; ++m)
#pragma unroll
    for (int n = 0; n < 4; ++n) acc[m][n] = f32x4{0.f, 0.f, 0.f, 0.f};

  bf16x8 a[4], b[4];

  asm volatile("s_waitcnt vmcnt(8)" ::: "memory");
  BAR();

#pragma unroll 1
  for (int t = 0; t < 14; ++t) {
    const int bc = t & 1;
    TILE(bc, bc ^ 1, t, 1, 1, 8, 8);
  }
  TILE(0, 1, 14, 1, 0, 8, 4);
  TILE(1, 0, 15, 0, 0, 0, 0);

  // ---- epilogue: repack C-tile through LDS -> coalesced 16B stores ----
  // (last TILE ends with BAR; all LDS reads done, safe to overwrite)
  u16* cl = &lds[0][0][0][0];  // viewed as [256][256] bf16 = 128 KiB exactly
  {
    const int fr = l & 15, fg = l >> 4;
#pragma unroll
    for (int m = 0; m < 8; ++m) {
      const int row0 = wr * 128 + m * 16 + fg * 4;          // + j
      const int s = (row0 >> 2) & 7;                        // const over j (row0%4==0)
#pragma unroll
      for (int n = 0; n < 4; ++n) {
        const int col = wc * 64 + n * 16 + fr;
        const int g = (col >> 3) ^ s;                       // 16B-granule XOR swizzle
        const int base = g * 8 + (col & 7);
#pragma unroll
        for (int j = 0; j < 4; ++j)
          cl[(row0 + j) * 256 + base] = f2bf(acc[m][n][j]);
      }
    }
  }
  BAR();
  {
    const int row = tid >> 1, half = tid & 1;               // 2 threads per row
    u16* Cz = C + (size_t)z * zstride;
    const size_t gbase = (size_t)(brow + row) * ldc + bcol + half * 128;
    const int s = (row >> 2) & 7;
#pragma unroll
    for (int i = 0; i < 16; ++i) {
      const int col16 = half * 16 + i;
      const int g = col16 ^ s;
      *reinterpret_cast<u16x8*>(Cz + gbase + i * 8) =
          *reinterpret_cast<const u16x8*>(cl + row * 256 + g * 8);
    }
  }
}

// ---- softmax1: reduce 16 split-K bf16 partials + row softmax -> bf16 attn ----
__global__ __launch_bounds__(256) void softmax1(const u16* __restrict__ Sp,
                                                u16* __restrict__ attn) {
  const int row = blockIdx.x, t = threadIdx.x;
  float s0 = 0.f, s1 = 0.f, s2 = 0.f, s3 = 0.f;
#pragma unroll
  for (int z = 0; z < 16; ++z) {
    u16x4 v = *reinterpret_cast<const u16x4*>(Sp + (size_t)z * 1024 * 1024 +
                                              (size_t)row * 1024 + t * 4);
    s0 += bf2f(v[0]); s1 += bf2f(v[1]); s2 += bf2f(v[2]); s3 += bf2f(v[3]);
  }
  __shared__ float red[256];
  red[t] = fmaxf(fmaxf(s0, s1), fmaxf(s2, s3));
  __syncthreads();
  for (int off = 128; off > 0; off >>= 1) {
    if (t < off) red[t] = fmaxf(red[t], red[t + off]);
    __syncthreads();
  }
  const float rowmax = red[0];
  __syncthreads();
  float e0 = __expf(s0 - rowmax), e1 = __expf(s1 - rowmax);
  float e2 = __expf(s2 - rowmax), e3 = __expf(s3 - rowmax);
  red[t] = e0 + e1 + e2 + e3;
  __syncthreads();
  for (int off = 128; off > 0; off >>= 1) {
    if (t < off) red[t] += red[t + off];
    __syncthreads();
  }
  const float inv = 1.0f / red[0];
  u16x4 o;
  o[0] = f2bf(e0 * inv); o[1] = f2bf(e1 * inv);
  o[2] = f2bf(e2 * inv); o[3] = f2bf(e3 * inv);
  *reinterpret_cast<u16x4*>(attn + (size_t)row * 1024 + t * 4) = o;
}

// ---- softmax2_final: row softmax over 16384, then per-64-group softmax + residual ----
__global__ __launch_bounds__(1024) void softmax2_final(const u16* __restrict__ Sc,
                                                       const float* __restrict__ X,
                                                       float* __restrict__ O) {
  const int row = blockIdx.x, t = threadIdx.x;
  const size_t base = (size_t)row * 16384 + (size_t)t * 16;
  u16x8 u0 = *reinterpret_cast<const u16x8*>(Sc + base);
  u16x8 u1 = *reinterpret_cast<const u16x8*>(Sc + base + 8);
  float v[16];
#pragma unroll
  for (int j = 0; j < 8; ++j) { v[j] = bf2f(u0[j]); v[8 + j] = bf2f(u1[j]); }
  float m = v[0];
#pragma unroll
  for (int j = 1; j < 16; ++j) m = fmaxf(m, v[j]);
  __shared__ float red[1024];
  red[t] = m;
  __syncthreads();
  for (int off = 512; off > 0; off >>= 1) {
    if (t < off) red[t] = fmaxf(red[t], red[t + off]);
    __syncthreads();
  }
  const float rowmax = red[0];
  __syncthreads();
  float e[16], sum = 0.f;
#pragma unroll
  for (int j = 0; j < 16; ++j) { e[j] = __expf(v[j] - rowmax); sum += e[j]; }
  red[t] = sum;
  __syncthreads();
  for (int off = 512; off > 0; off >>= 1) {
    if (t < off) red[t] += red[t + off];
    __syncthreads();
  }
  const float inv = 1.0f / red[0];  // y[j] = e[j] * inv

  float em = e[0];
#pragma unroll
  for (int j = 1; j < 16; ++j) em = fmaxf(em, e[j]);
  em = fmaxf(em, __shfl_xor(em, 1, 64));
  em = fmaxf(em, __shfl_xor(em, 2, 64));
  const float ym = em * inv;

  float eg[16], sg = 0.f;
#pragma unroll
  for (int j = 0; j < 16; ++j) { eg[j] = __expf(e[j] * inv - ym); sg += eg[j]; }
  sg += __shfl_xor(sg, 1, 64);
  sg += __shfl_xor(sg, 2, 64);
  const float inv2 = 1.0f / sg;

#pragma unroll
  for (int q = 0; q < 4; ++q) {
    float4 xv = *reinterpret_cast<const float4*>(X + base + q * 4);
    float4 o;
    o.x = xv.x + eg[q * 4 + 0] * inv2;
    o.y = xv.y + eg[q * 4 + 1] * inv2;
    o.z = xv.z + eg[q * 4 + 2] * inv2;
    o.w = xv.w + eg[q * 4 + 3] * inv2;
    *reinterpret_cast<float4*>(O + base + q * 4) = o;
  }
}

extern "C" void kernel_launch(void* const* d_in, const int* in_sizes, int n_in,
                              void* d_out, int out_size, void* d_ws, size_t ws_size,
                              hipStream_t stream) {
  const float* x = (const float*)d_in[0];
  float* out = (float*)d_out;
  char* ws = (char*)d_ws;

  // Workspace layout (98 MiB):
  //   P0 [ 0,32): A16 (x as bf16); dead after t2 -> Sc (GEMM2 out)
  //   P1 [32,64): Bt1 (1024x16384), then Bt2 (16384x1024)
  //   P2 [64,96): Sp16 split-K bf16 partials (16 x 1024x1024); dead after softmax1
  //   P3 [96,98): attn bf16 (1024x1024)
  const size_t MiB = 1u << 20;
  if (ws_size < 98 * MiB) return;
  u16* A16 = (u16*)(ws);
  u16* Bt = (u16*)(ws + 32 * MiB);
  u16* Sp16 = (u16*)(ws + 64 * MiB);
  u16* attn = (u16*)(ws + 96 * MiB);
  u16* Sc = A16;  // GEMM2 output overlays A16 (dead by then)

  prep_t1<<<dim3(16, 256), dim3(16, 32), 0, stream>>>(x, A16, Bt);
  gemm256<0><<<256, 512, 0, stream>>>(A16, Bt, Sp16, 16384, 16384, 1024,
                                      (long)1024 * 1024);
  softmax1<<<1024, 256, 0, stream>>>(Sp16, attn);
  t2_bf16<<<dim3(256, 16), dim3(16, 32), 0, stream>>>(A16, Bt);
  gemm256<1><<<256, 512, 0, stream>>>(attn, Bt, Sc, 1024, 1024, 16384, 0);
  softmax2_final<<<1024, 1024, 0, stream>>>(Sc, x, out);
}